// Round 10
// baseline (227.690 us; speedup 1.0000x reference)
//
#include <hip/hip_runtime.h>
#include <math.h>

#define NV 4096      // variable nodes
#define MC 2048      // check nodes
#define DV 3
#define DC 6
#define NE (NV * DV) // 12288 edges
#define NB 2048      // batch
#define NITER 5
#define TPB 1024     // 16 waves/block; 2 blocks/CU -> 32 waves/CU (80KB LDS)

// Build per-check-node edge lists (slot order arbitrary due to atomics).
__global__ __launch_bounds__(256) void build_cn(const int* __restrict__ cn_idx,
                                                int* __restrict__ cn_edges,
                                                int* __restrict__ cn_cnt) {
    int e = blockIdx.x * 256 + threadIdx.x;
    if (e < NE) {
        int m = cn_idx[e];
        int slot = atomicAdd(&cn_cnt[m], 1);
        cn_edges[m * DC + slot] = e;
    }
}

// Sort each CN's 6 edges ascending (deterministic, matches ref edge order);
// emit per-CN tables: word index into the padded msg array (4*vn + slot) and
// the edge weight, both CN-contiguous for coalesced reads.
__global__ __launch_bounds__(256) void sort_cn(int* __restrict__ cn_edges,
                                               const float* __restrict__ ew,
                                               int* __restrict__ cn_widx,
                                               float* __restrict__ cn_w) {
    int m = blockIdx.x * 256 + threadIdx.x;
    if (m < MC) {
        int v[DC];
        for (int j = 0; j < DC; ++j) v[j] = cn_edges[m * DC + j];
        for (int i = 1; i < DC; ++i) {
            int key = v[i]; int j = i - 1;
            while (j >= 0 && v[j] > key) { v[j + 1] = v[j]; --j; }
            v[j + 1] = key;
        }
        for (int j = 0; j < DC; ++j) {
            int e = v[j];
            cn_widx[m * DC + j] = 4 * (e / DV) + (e % DV);  // < 16384, fits u16
            cn_w[m * DC + j]    = ew[e];
        }
    }
}

// One workgroup per batch element. LDS: tot[NV] (unpadded, bank-uniform) +
// msg[NV][4] (VN-major padded -> one b128 read per VN). Each thread's 2 CNs'
// outgoing messages persist in REGISTERS across iterations, so the VN phase
// needs no random access at all and the CN phase reads totals directly.
//   CN: mw = (tot[v] - mprev)*w  (== ref msg_vn*w bit-exactly);
//       product-domain update: u=e^{-|mw|}, Pp/Pm excl-products of (1+-u),
//       val = ln((Pp+Pm)/max(Pp-Pm, 2^-23*Pp))  [== ref clip at 1-2^-23];
//       sign = bit-parity XOR (exact). [absmax 1.0 proven R5/R7/R8]
//   VN: tot = llr + ((c0+c1)+c2) -- same assoc order as np's scatter-add.
__global__ __launch_bounds__(TPB, 8) void bp_iter(const float* __restrict__ noise_r,
                                                  const int* __restrict__ cn_widx,
                                                  const float* __restrict__ cn_w,
                                                  float* __restrict__ out) {
    extern __shared__ float lds[];
    float* tot = lds;          // NV words
    float* msg = lds + NV;     // 4*NV words, row n = words [4n, 4n+4)

    const int b = blockIdx.x;
    const int t = threadIdx.x;

    const float NO   = (float)0.3981071705534972;          // 1/(R*2*10^(EbNo/10))
    const float NSTD = sqrtf((float)(0.3981071705534972 * 0.5));

    // Hoist word-index table into 6 packed regs (2 x u16 each).
    unsigned wpk[MC / TPB][3];
#pragma unroll
    for (int c = 0; c < MC / TPB; ++c) {
        const int* wp = cn_widx + (t + TPB * c) * DC;
#pragma unroll
        for (int i = 0; i < 3; ++i)
            wpk[c][i] = (unsigned)wp[2 * i] | ((unsigned)wp[2 * i + 1] << 16);
    }
#define WJ(c, j) ((int)((wpk[c][(j) >> 1] >> (((j) & 1) * 16)) & 0xffffu))

    // ---- channel LLRs; tot starts as llr ----
    float llr[NV / TPB];
    const float* nb = noise_r + (size_t)b * NV;
#pragma unroll
    for (int k = 0; k < NV / TPB; ++k) {
        int n = t + TPB * k;
        float y = 1.0f + NSTD * nb[n];
        float l = (4.0f * y) / NO;
        llr[k] = l;
        tot[n] = l;
    }

    // persistent per-thread CN outgoing messages (0 before first iter)
    float mprev[MC / TPB][DC];
#pragma unroll
    for (int c = 0; c < MC / TPB; ++c)
#pragma unroll
        for (int j = 0; j < DC; ++j) mprev[c][j] = 0.0f;

    __syncthreads();

    for (int it = 0; it < NITER; ++it) {
        // ---- CN phase: each thread owns 2 check nodes ----
#pragma unroll
        for (int c = 0; c < MC / TPB; ++c) {
            const int m = t + TPB * c;
            const float* wr = cn_w + m * DC;     // contiguous, L2-resident
            float u[DC];
            unsigned spack = 0u;
#pragma unroll
            for (int j = 0; j < DC; ++j) {
                float mw = (tot[WJ(c, j) >> 2] - mprev[c][j]) * wr[j];
                u[j] = __expf(-fabsf(mw));
                spack |= ((__float_as_uint(mw) >> 31) & 1u) << j;
            }
            unsigned par = __popc(spack) & 1u;

            // suffix products of (1+-u), then running prefix
            float sp[DC], sm[DC];
            sp[DC - 1] = 1.0f; sm[DC - 1] = 1.0f;
#pragma unroll
            for (int j = DC - 2; j >= 0; --j) {
                sp[j] = sp[j + 1] * (1.0f + u[j + 1]);
                sm[j] = sm[j + 1] * (1.0f - u[j + 1]);
            }
            float rp = 1.0f, rm = 1.0f;
#pragma unroll
            for (int j = 0; j < DC; ++j) {
                float Pp  = rp * sp[j];
                float Pm  = rm * sm[j];
                float num = Pp + Pm;
                float den = fmaxf(Pp - Pm, 0x1.0p-23f * Pp);   // == ref clip 1-2^-23
                float val = __logf(__fdividef(num, den));      // >= 0
                unsigned sg = ((par ^ (spack >> j)) & 1u) << 31;
                float sval = __uint_as_float(__float_as_uint(val) | sg);
                mprev[c][j] = sval;
                msg[WJ(c, j)] = sval;                          // random scatter
                rp *= (1.0f + u[j]);
                rm *= (1.0f - u[j]);
            }
        }
        __syncthreads();

        // ---- VN phase: one b128 read per VN, conflict-free ----
        if (it < NITER - 1) {
#pragma unroll
            for (int k = 0; k < NV / TPB; ++k) {
                int n = t + TPB * k;
                float4 r = *(const float4*)&msg[4 * n];        // slots 0..2 + pad
                tot[n] = llr[k] + ((r.x + r.y) + r.z);
            }
            __syncthreads();
        } else {
#pragma unroll
            for (int k = 0; k < NV / TPB; ++k) {
                int n = t + TPB * k;
                float4 r = *(const float4*)&msg[4 * n];
                out[(size_t)b * NV + n] = llr[k] + ((r.x + r.y) + r.z);
            }
        }
    }
#undef WJ
}

extern "C" void kernel_launch(void* const* d_in, const int* in_sizes, int n_in,
                              void* d_out, int out_size, void* d_ws, size_t ws_size,
                              hipStream_t stream) {
    const float* noise_r = (const float*)d_in[0];
    // d_in[1] = noise_i (unused by reference)
    const float* ew      = (const float*)d_in[2];
    // d_in[3] = vn_idx: known structure e // 3 (edges contiguous per VN)
    const int*   cn_idx  = (const int*)d_in[4];
    float* out = (float*)d_out;

    int*   cn_edges = (int*)d_ws;            // NE ints
    int*   cn_cnt   = cn_edges + NE;         // MC ints
    int*   cn_widx  = cn_cnt + MC;           // NE ints
    float* cn_w     = (float*)(cn_widx + NE);// NE floats

    hipMemsetAsync(cn_cnt, 0, MC * sizeof(int), stream);
    build_cn<<<(NE + 255) / 256, 256, 0, stream>>>(cn_idx, cn_edges, cn_cnt);
    sort_cn<<<(MC + 255) / 256, 256, 0, stream>>>(cn_edges, ew, cn_widx, cn_w);

    const size_t shbytes = (size_t)(NV + 4 * NV) * sizeof(float);  // 80 KB
    bp_iter<<<NB, TPB, shbytes, stream>>>(noise_r, cn_widx, cn_w, out);
}

// Round 11
// 171.789 us; speedup vs baseline: 1.3254x; 1.3254x over previous
//
#include <hip/hip_runtime.h>
#include <math.h>

#define NV 4096      // variable nodes
#define MC 2048      // check nodes
#define DV 3
#define DC 6
#define NE (NV * DV) // 12288 edges
#define NB 2048      // batch
#define NITER 5
#define TPB 1024     // 16 waves/block
#define SPB 2        // samples (batch elems) per block: ILP x2, shared tables

// Build per-check-node edge lists (slot order arbitrary due to atomics).
__global__ __launch_bounds__(256) void build_cn(const int* __restrict__ cn_idx,
                                                int* __restrict__ cn_edges,
                                                int* __restrict__ cn_cnt) {
    int e = blockIdx.x * 256 + threadIdx.x;
    if (e < NE) {
        int m = cn_idx[e];
        int slot = atomicAdd(&cn_cnt[m], 1);
        cn_edges[m * DC + slot] = e;
    }
}

// Sort each CN's 6 edges ascending -> deterministic, matches ref edge order.
__global__ __launch_bounds__(256) void sort_cn(int* __restrict__ cn_edges) {
    int m = blockIdx.x * 256 + threadIdx.x;
    if (m < MC) {
        int v[DC];
        for (int j = 0; j < DC; ++j) v[j] = cn_edges[m * DC + j];
        for (int i = 1; i < DC; ++i) {
            int key = v[i]; int j = i - 1;
            while (j >= 0 && v[j] > key) { v[j + 1] = v[j]; --j; }
            v[j + 1] = key;
        }
        for (int j = 0; j < DC; ++j) cn_edges[m * DC + j] = v[j];
    }
}

// One workgroup per TWO batch elements; two 48 KB edge-major message arrays
// in dynamic LDS (96 KB -> 1 block/CU). Each thread owns 2 CNs and 4 VNs of
// BOTH samples: two independent dependency chains per thread (ILP x2
// replaces the occupancy R8 lost; no hot state persists across iterations
// -> no RMW spill, R9 lesson). Graph tables eidx/ew are read once per block
// for both samples.
//
// CN update in product domain: u = e^{-|mw|}; Pp/Pm = exclusion products of
// (1+u)/(1-u); 2*atanh(Pm/Pp) = ln((Pp+Pm)/(Pp-Pm)); ref's clip at
// float32(1-1e-7) = 1-2^-23 == den = max(Pp-Pm, 2^-23*Pp). Sign = bit
// parity XOR (exact). [absmax 1.0 proven R5/R7/R8/R9]
__global__ __launch_bounds__(TPB, 4) void bp_iter(const float* __restrict__ noise_r,
                                                  const float* __restrict__ ew,
                                                  const int* __restrict__ cn_edges,
                                                  float* __restrict__ out) {
    extern __shared__ float lds[];
    float* __restrict__ msg0 = lds;          // sample 0: NE words
    float* __restrict__ msg1 = lds + NE;     // sample 1: NE words

    const int t  = threadIdx.x;
    const int b0 = SPB * blockIdx.x;
    const int b1 = b0 + 1;

    const float NO   = (float)0.3981071705534972;          // 1/(R*2*10^(EbNo/10))
    const float NSTD = sqrtf((float)(0.3981071705534972 * 0.5));

    // Hoist per-CN edge lists into registers (12 VGPR; shared by both samples).
    int eidx[MC / TPB][DC];
#pragma unroll
    for (int c = 0; c < MC / TPB; ++c)
#pragma unroll
        for (int j = 0; j < DC; ++j)
            eidx[c][j] = cn_edges[(t + TPB * c) * DC + j];

    float llr0[NV / TPB], llr1[NV / TPB];
    const float* nb0 = noise_r + (size_t)b0 * NV;
    const float* nb1 = noise_r + (size_t)b1 * NV;
#pragma unroll
    for (int k = 0; k < NV / TPB; ++k) {
        int n = t + TPB * k;
        float w0 = ew[3 * n + 0], w1 = ew[3 * n + 1], w2 = ew[3 * n + 2];
        float l0 = (4.0f * (1.0f + NSTD * nb0[n])) / NO;
        float l1 = (4.0f * (1.0f + NSTD * nb1[n])) / NO;
        llr0[k] = l0;
        llr1[k] = l1;
        msg0[3 * n + 0] = l0 * w0; msg0[3 * n + 1] = l0 * w1; msg0[3 * n + 2] = l0 * w2;
        msg1[3 * n + 0] = l1 * w0; msg1[3 * n + 1] = l1 * w1; msg1[3 * n + 2] = l1 * w2;
    }
    __syncthreads();

    for (int it = 0; it < NITER; ++it) {
        // ---- CN phase: 2 check nodes x 2 samples per thread ----
#pragma unroll
        for (int c = 0; c < MC / TPB; ++c) {
            float a[SPB][DC], bb[SPB][DC];
            unsigned sp0 = 0u, sp1 = 0u;
#pragma unroll
            for (int j = 0; j < DC; ++j) {
                float mwA = msg0[eidx[c][j]];
                float mwB = msg1[eidx[c][j]];
                float uA = __expf(-fabsf(mwA));
                float uB = __expf(-fabsf(mwB));
                a[0][j] = 1.0f + uA;  bb[0][j] = 1.0f - uA;
                a[1][j] = 1.0f + uB;  bb[1][j] = 1.0f - uB;
                sp0 |= ((__float_as_uint(mwA) >> 31) & 1u) << j;
                sp1 |= ((__float_as_uint(mwB) >> 31) & 1u) << j;
            }
            unsigned par0 = __popc(sp0) & 1u;
            unsigned par1 = __popc(sp1) & 1u;

            // suffix products, then running prefix (both samples interleaved)
            float sfp[SPB][DC], sfm[SPB][DC];
            sfp[0][DC - 1] = 1.0f; sfm[0][DC - 1] = 1.0f;
            sfp[1][DC - 1] = 1.0f; sfm[1][DC - 1] = 1.0f;
#pragma unroll
            for (int j = DC - 2; j >= 0; --j) {
                sfp[0][j] = sfp[0][j + 1] * a[0][j + 1];
                sfm[0][j] = sfm[0][j + 1] * bb[0][j + 1];
                sfp[1][j] = sfp[1][j + 1] * a[1][j + 1];
                sfm[1][j] = sfm[1][j + 1] * bb[1][j + 1];
            }
            float rpA = 1.0f, rmA = 1.0f, rpB = 1.0f, rmB = 1.0f;
#pragma unroll
            for (int j = 0; j < DC; ++j) {
                float PpA = rpA * sfp[0][j], PmA = rmA * sfm[0][j];
                float PpB = rpB * sfp[1][j], PmB = rmB * sfm[1][j];
                float denA = fmaxf(PpA - PmA, 0x1.0p-23f * PpA);  // == ref clip
                float denB = fmaxf(PpB - PmB, 0x1.0p-23f * PpB);
                float valA = __logf(__fdividef(PpA + PmA, denA)); // >= 0
                float valB = __logf(__fdividef(PpB + PmB, denB));
                unsigned sgA = ((par0 ^ (sp0 >> j)) & 1u) << 31;
                unsigned sgB = ((par1 ^ (sp1 >> j)) & 1u) << 31;
                msg0[eidx[c][j]] = __uint_as_float(__float_as_uint(valA) | sgA);
                msg1[eidx[c][j]] = __uint_as_float(__float_as_uint(valB) | sgB);
                rpA *= a[0][j]; rmA *= bb[0][j];
                rpB *= a[1][j]; rmB *= bb[1][j];
            }
        }
        __syncthreads();

        // ---- VN phase: 4 VNs x 2 samples per thread ----
        if (it < NITER - 1) {
#pragma unroll
            for (int k = 0; k < NV / TPB; ++k) {
                int n = t + TPB * k;
                float w0 = ew[3 * n + 0], w1 = ew[3 * n + 1], w2 = ew[3 * n + 2];
                float cA0 = msg0[3 * n + 0], cA1 = msg0[3 * n + 1], cA2 = msg0[3 * n + 2];
                float cB0 = msg1[3 * n + 0], cB1 = msg1[3 * n + 1], cB2 = msg1[3 * n + 2];
                float totA = llr0[k] + (cA0 + cA1 + cA2);
                float totB = llr1[k] + (cB0 + cB1 + cB2);
                msg0[3 * n + 0] = (totA - cA0) * w0;
                msg0[3 * n + 1] = (totA - cA1) * w1;
                msg0[3 * n + 2] = (totA - cA2) * w2;
                msg1[3 * n + 0] = (totB - cB0) * w0;
                msg1[3 * n + 1] = (totB - cB1) * w1;
                msg1[3 * n + 2] = (totB - cB2) * w2;
            }
            __syncthreads();
        } else {
#pragma unroll
            for (int k = 0; k < NV / TPB; ++k) {
                int n = t + TPB * k;
                float cA0 = msg0[3 * n + 0], cA1 = msg0[3 * n + 1], cA2 = msg0[3 * n + 2];
                float cB0 = msg1[3 * n + 0], cB1 = msg1[3 * n + 1], cB2 = msg1[3 * n + 2];
                out[(size_t)b0 * NV + n] = llr0[k] + (cA0 + cA1 + cA2);
                out[(size_t)b1 * NV + n] = llr1[k] + (cB0 + cB1 + cB2);
            }
        }
    }
}

extern "C" void kernel_launch(void* const* d_in, const int* in_sizes, int n_in,
                              void* d_out, int out_size, void* d_ws, size_t ws_size,
                              hipStream_t stream) {
    const float* noise_r = (const float*)d_in[0];
    // d_in[1] = noise_i (unused by reference)
    const float* ew      = (const float*)d_in[2];
    // d_in[3] = vn_idx: known structure e // 3 (edges contiguous per VN)
    const int*   cn_idx  = (const int*)d_in[4];
    float* out = (float*)d_out;

    int* cn_edges = (int*)d_ws;        // NE ints
    int* cn_cnt   = cn_edges + NE;     // MC ints

    const size_t shbytes = (size_t)SPB * NE * sizeof(float);   // 96 KB
    static bool attr_set = false;  // host-side only; idempotent, not a stream op
    if (!attr_set) {
        hipFuncSetAttribute((const void*)bp_iter,
                            hipFuncAttributeMaxDynamicSharedMemorySize,
                            (int)shbytes);
        attr_set = true;
    }

    hipMemsetAsync(cn_cnt, 0, MC * sizeof(int), stream);
    build_cn<<<(NE + 255) / 256, 256, 0, stream>>>(cn_idx, cn_edges, cn_cnt);
    sort_cn<<<(MC + 255) / 256, 256, 0, stream>>>(cn_edges);
    bp_iter<<<NB / SPB, TPB, shbytes, stream>>>(noise_r, ew, cn_edges, out);
}